// Round 1
// baseline (1522.457 us; speedup 1.0000x reference)
//
#include <hip/hip_runtime.h>
#include <hip/hip_bf16.h>
#include <cstdint>
#include <cstddef>

// Problem dims (fixed).
#define BATCH   2048
#define INDIM   1024
#define HIDDIM  1024
#define TSTEPS  32
#define OUTDIM  512
#define KDIM    1024
#define CHUNK   8          // steps of hs buffered before the output GEMM

using bf16 = __hip_bfloat16;
typedef __bf16 bf16x8 __attribute__((ext_vector_type(8)));
typedef float  f32x4  __attribute__((ext_vector_type(4)));

// ---------------------------------------------------------------------------
// async global -> LDS, 16B per lane. LDS dest is wave-uniform base + lane*16.
// ---------------------------------------------------------------------------
__device__ __forceinline__ void async_load16(const void* g, void* l) {
    __builtin_amdgcn_global_load_lds(
        (__attribute__((address_space(1))) unsigned int*)(g),
        (__attribute__((address_space(3))) unsigned int*)(l),
        16, 0, 0);
}

// ---------------------------------------------------------------------------
// m97-structure GEMM: C[M][N] = A[M][K] @ B[N][K]^T (+bias, epilogue variants)
// 128x128 tile, BK=32, 4 waves, 16x16x32 bf16 MFMA, global_load_lds staging.
// EPI 0: gates  -> f32  C[row*4096+col] = acc + bias[col]
// EPI 1: h0     -> bf16 C[row*1024+col] = relu(acc + bias[col])
// EPI 2: outGEMM-> f32  C[remap(row)*512+col] = acc + bias[col]
//                  remap: row=(b*8+tau) -> b*32 + t0 + tau
// ---------------------------------------------------------------------------
template <int EPI>
__launch_bounds__(256, 2)
__global__ void gemm_k1024(const bf16* __restrict__ A, const bf16* __restrict__ Bm,
                           const float* __restrict__ bias, void* __restrict__ Cout,
                           int t0) {
    __shared__ __align__(16) bf16 lA[128 * 32];
    __shared__ __align__(16) bf16 lB[128 * 32];

    const int tid  = threadIdx.x;
    const int wid  = tid >> 6;
    const int lane = tid & 63;
    const int m0   = blockIdx.y * 128;
    const int n0   = blockIdx.x * 128;
    const int wr   = wid >> 1;        // wave row (0..1) -> 64 rows
    const int wc   = wid & 1;         // wave col (0..1) -> 64 cols
    const int lrow = lane & 15;
    const int lkg  = lane >> 4;       // k-group 0..3

    f32x4 acc[4][4];
#pragma unroll
    for (int i = 0; i < 4; ++i)
#pragma unroll
        for (int j = 0; j < 4; ++j) acc[i][j] = (f32x4){0.f, 0.f, 0.f, 0.f};

    // staging: chunk = q*256 + tid; row = chunk>>2 (of 128); col8 = (chunk&3)*8
    const int r0 = tid >> 2;
    const int c0 = (tid & 3) * 8;
    const bf16* gA0 = A  + (size_t)(m0 + r0) * KDIM + c0;
    const bf16* gA1 = A  + (size_t)(m0 + 64 + r0) * KDIM + c0;
    const bf16* gB0 = Bm + (size_t)(n0 + r0) * KDIM + c0;
    const bf16* gB1 = Bm + (size_t)(n0 + 64 + r0) * KDIM + c0;
    bf16* lAq0 = &lA[(size_t)(wid * 64) * 8];
    bf16* lAq1 = &lA[(size_t)(256 + wid * 64) * 8];
    bf16* lBq0 = &lB[(size_t)(wid * 64) * 8];
    bf16* lBq1 = &lB[(size_t)(256 + wid * 64) * 8];

    for (int kt = 0; kt < KDIM / 32; ++kt) {
        const int ko = kt * 32;
        async_load16(gA0 + ko, lAq0);
        async_load16(gA1 + ko, lAq1);
        async_load16(gB0 + ko, lBq0);
        async_load16(gB1 + ko, lBq1);
        __syncthreads();   // compiler drains vmcnt(0) before s_barrier

        bf16x8 af[4], bfr[4];
#pragma unroll
        for (int mi = 0; mi < 4; ++mi)
            af[mi] = *(const bf16x8*)&lA[(size_t)(wr * 64 + mi * 16 + lrow) * 32 + lkg * 8];
#pragma unroll
        for (int ni = 0; ni < 4; ++ni)
            bfr[ni] = *(const bf16x8*)&lB[(size_t)(wc * 64 + ni * 16 + lrow) * 32 + lkg * 8];

#pragma unroll
        for (int mi = 0; mi < 4; ++mi)
#pragma unroll
            for (int ni = 0; ni < 4; ++ni)
                acc[mi][ni] = __builtin_amdgcn_mfma_f32_16x16x32_bf16(
                    af[mi], bfr[ni], acc[mi][ni], 0, 0, 0);
        __syncthreads();
    }

    // epilogue: D row = (lane>>4)*4 + r, col = lane&15  [measured m89/m91]
#pragma unroll
    for (int mi = 0; mi < 4; ++mi) {
#pragma unroll
        for (int ni = 0; ni < 4; ++ni) {
            const f32x4 v = acc[mi][ni];
            const int c = n0 + wc * 64 + ni * 16 + lrow;
            const int rb = m0 + wr * 64 + mi * 16 + lkg * 4;
            const float bs = bias[c];
#pragma unroll
            for (int r = 0; r < 4; ++r) {
                const float val = v[r] + bs;
                const int row = rb + r;
                if constexpr (EPI == 0) {
                    ((float*)Cout)[(size_t)row * 4096 + c] = val;
                } else if constexpr (EPI == 1) {
                    ((bf16*)Cout)[(size_t)row * 1024 + c] =
                        __float2bfloat16(val > 0.f ? val : 0.f);
                } else {
                    const int orow = (row >> 3) * TSTEPS + t0 + (row & 7);
                    ((float*)Cout)[(size_t)orow * OUTDIM + c] = val;
                }
            }
        }
    }
}

// ---------------------------------------------------------------------------
// pointwise LSTM cell: gates[B][4096] f32 -> c (f32), h (bf16), hs chunk slot
// ---------------------------------------------------------------------------
__global__ void lstm_cell(const float* __restrict__ gates, float* __restrict__ c,
                          bf16* __restrict__ h, bf16* __restrict__ hs, int t) {
    const int idx = blockIdx.x * 256 + threadIdx.x;   // over B*H = 2M
    const int b = idx >> 10;
    const int j = idx & 1023;
    const float* g = gates + (size_t)b * 4096;
    const float gi = g[j];
    const float gf = g[j + 1024];
    const float gg = g[j + 2048];
    const float go = g[j + 3072];
    const float si = 1.f / (1.f + __expf(-gi));
    const float sf = 1.f / (1.f + __expf(-gf));
    const float tg = tanhf(gg);
    const float so = 1.f / (1.f + __expf(-go));
    const float cold = (t == 0) ? 0.f : c[idx];
    const float cn = sf * cold + si * tg;
    const float hn = so * tanhf(cn);
    c[idx] = cn;
    const bf16 hb = __float2bfloat16(hn);
    h[idx] = hb;
    hs[(size_t)((b << 3) + (t & 7)) * 1024 + j] = hb;
}

// ---------------------------------------------------------------------------
// prep kernels
// ---------------------------------------------------------------------------
__global__ void prep_wc(const float* __restrict__ Wih, const float* __restrict__ Whh,
                        const float* __restrict__ bih, const float* __restrict__ bhh,
                        bf16* __restrict__ Wc, float* __restrict__ bc) {
    const int base = (blockIdx.x * 256 + threadIdx.x) * 4;   // over 4H*H
    const float4 a = *(const float4*)(Wih + base);
    const float4 b = *(const float4*)(Whh + base);
    Wc[base + 0] = __float2bfloat16(a.x + b.x);
    Wc[base + 1] = __float2bfloat16(a.y + b.y);
    Wc[base + 2] = __float2bfloat16(a.z + b.z);
    Wc[base + 3] = __float2bfloat16(a.w + b.w);
    if (base < 4096) {
#pragma unroll
        for (int r = 0; r < 4; ++r) bc[base + r] = bih[base + r] + bhh[base + r];
    }
}

__global__ void f2b(const float* __restrict__ s, bf16* __restrict__ d, int n) {
    const int i = (blockIdx.x * 256 + threadIdx.x) * 4;
    if (i < n) {
        const float4 v = *(const float4*)(s + i);
        d[i + 0] = __float2bfloat16(v.x);
        d[i + 1] = __float2bfloat16(v.y);
        d[i + 2] = __float2bfloat16(v.z);
        d[i + 3] = __float2bfloat16(v.w);
    }
}

// ---------------------------------------------------------------------------
extern "C" void kernel_launch(void* const* d_in, const int* in_sizes, int n_in,
                              void* d_out, int out_size, void* d_ws, size_t ws_size,
                              hipStream_t stream) {
    const float* x     = (const float*)d_in[0];
    const float* W_in  = (const float*)d_in[1];
    const float* b_in  = (const float*)d_in[2];
    const float* W_ih  = (const float*)d_in[3];
    const float* b_ih  = (const float*)d_in[4];
    const float* W_hh  = (const float*)d_in[5];
    const float* b_hh  = (const float*)d_in[6];
    const float* W_out = (const float*)d_in[7];
    const float* b_out = (const float*)d_in[8];
    float* out = (float*)d_out;

    // workspace carve (~91 MB total)
    char* ws = (char*)d_ws;
    bf16* Wc   = (bf16*)ws;  ws += (size_t)4096 * 1024 * 2;       //  8 MB
    bf16* Wi_b = (bf16*)ws;  ws += (size_t)1024 * 1024 * 2;       //  2 MB
    bf16* Wo_b = (bf16*)ws;  ws += (size_t)512  * 1024 * 2;       //  1 MB
    bf16* x_b  = (bf16*)ws;  ws += (size_t)2048 * 1024 * 2;       //  4 MB
    bf16* h    = (bf16*)ws;  ws += (size_t)2048 * 1024 * 2;       //  4 MB
    bf16* hs   = (bf16*)ws;  ws += (size_t)2048 * CHUNK * 1024 * 2; // 32 MB
    float* bc  = (float*)ws; ws += (size_t)4096 * 4;              // 16 KB
    float* cst = (float*)ws; ws += (size_t)2048 * 1024 * 4;       //  8 MB
    float* gates = (float*)ws; ws += (size_t)2048 * 4096 * 4;     // 32 MB

    // 1) prep: Wc = bf16(W_ih + W_hh), bc = b_ih + b_hh; bf16 copies of x/W_in/W_out
    prep_wc<<<4096 * 1024 / (256 * 4), 256, 0, stream>>>(W_ih, W_hh, b_ih, b_hh, Wc, bc);
    f2b<<<2048 * 1024 / (256 * 4), 256, 0, stream>>>(x, x_b, 2048 * 1024);
    f2b<<<1024 * 1024 / (256 * 4), 256, 0, stream>>>(W_in, Wi_b, 1024 * 1024);
    f2b<<<512 * 1024 / (256 * 4), 256, 0, stream>>>(W_out, Wo_b, 512 * 1024);

    // 2) h0 = relu(x @ W_in^T + b_in)
    {
        dim3 g(HIDDIM / 128, BATCH / 128);   // (8,16)
        gemm_k1024<1><<<g, 256, 0, stream>>>(x_b, Wi_b, b_in, h, 0);
    }

    // 3) T recurrent steps
    for (int t = 0; t < TSTEPS; ++t) {
        {
            dim3 g(4096 / 128, BATCH / 128); // (32,16)
            gemm_k1024<0><<<g, 256, 0, stream>>>(h, Wc, bc, gates, 0);
        }
        lstm_cell<<<BATCH * HIDDIM / 256, 256, 0, stream>>>(gates, cst, h, hs, t);
        if ((t & (CHUNK - 1)) == (CHUNK - 1)) {
            // out rows b*32 + t0 + tau for this chunk
            dim3 g(OUTDIM / 128, BATCH * CHUNK / 128); // (4,128)
            gemm_k1024<2><<<g, 256, 0, stream>>>(hs, Wo_b, b_out, out, t - (CHUNK - 1));
        }
    }
    (void)in_sizes; (void)n_in; (void)out_size; (void)ws_size;
}

// Round 2
// 1485.106 us; speedup vs baseline: 1.0252x; 1.0252x over previous
//
#include <hip/hip_runtime.h>
#include <hip/hip_bf16.h>
#include <cstdint>
#include <cstddef>

// Problem dims (fixed).
#define BATCH   2048
#define INDIM   1024
#define HIDDIM  1024
#define TSTEPS  32
#define OUTDIM  512
#define KDIM    1024
#define CHUNK   8          // steps of hs buffered before the output GEMM

using bf16 = __hip_bfloat16;
typedef __bf16 bf16x8 __attribute__((ext_vector_type(8)));
typedef float  f32x4  __attribute__((ext_vector_type(4)));

// ---------------------------------------------------------------------------
// async global -> LDS, 16B per lane. LDS dest is wave-uniform base + lane*16.
// ---------------------------------------------------------------------------
__device__ __forceinline__ void async_load16(const void* g, void* l) {
    __builtin_amdgcn_global_load_lds(
        (__attribute__((address_space(1))) unsigned int*)(g),
        (__attribute__((address_space(3))) unsigned int*)(l),
        16, 0, 0);
}

__device__ __forceinline__ float sigf(float x) {
    return 1.f / (1.f + __expf(-x));                // stable both tails
}
__device__ __forceinline__ float tanh_stable(float x) {
    const float a = __builtin_fabsf(x);
    const float e = __expf(2.f * a);                // inf for a>44 -> r=1
    const float r = 1.f - 2.f / (e + 1.f);
    return __builtin_copysignf(r, x);
}

// ---------------------------------------------------------------------------
// m97-structure GEMM: C[M][N] = A[M][K] @ B[N][K]^T, 128x128 tile, BK=32,
// 4 waves, 16x16x32 bf16 MFMA, global_load_lds staging.
// EPI 0: fused gates+LSTM-cell. Bm rows permuted p=j*4+g (g in i,f,g,o order)
//        -> each lane-quad col group holds all 4 gates of one j; acc staged
//        to LDS (2 passes of 64 rows), cell computed per (row,j), writes
//        cstate (f32), hout (bf16), hs slot (bf16). No gates round-trip.
// EPI 1: h0 -> bf16  C[row*1024+col] = relu(acc + bias[col])
// EPI 2: outGEMM -> f32 C[remap(row)*512+col]; remap row=(b*8+tau) -> b*32+t0+tau
// ---------------------------------------------------------------------------
template <int EPI>
__launch_bounds__(256, 2)
__global__ void gemm_k1024(const bf16* __restrict__ A, const bf16* __restrict__ Bm,
                           const float* __restrict__ bias, void* __restrict__ Cout,
                           float* __restrict__ cstate, bf16* __restrict__ hout,
                           bf16* __restrict__ hsb, int tpar) {
    // LDS: K-loop uses first 16 KB (lA 8K | lB 8K); EPI0 epilogue reuses the
    // whole buffer as a [64][132] f32 staging tile (33792 B). Pitch 132 makes
    // the lkg-strided ds_write pattern 2-way (free) instead of 4-way.
    constexpr int SMEM_BYTES = (EPI == 0) ? 64 * 132 * 4 : 16384;
    __shared__ __align__(16) char smem[SMEM_BYTES];
    bf16* lA = (bf16*)smem;
    bf16* lB = (bf16*)(smem + 8192);

    const int tid  = threadIdx.x;
    const int wid  = tid >> 6;
    const int lane = tid & 63;
    const int m0   = blockIdx.y * 128;
    const int n0   = blockIdx.x * 128;
    const int wr   = wid >> 1;        // wave row (0..1) -> 64 rows
    const int wc   = wid & 1;         // wave col (0..1) -> 64 cols
    const int lrow = lane & 15;
    const int lkg  = lane >> 4;       // k-group 0..3

    f32x4 acc[4][4];
#pragma unroll
    for (int i = 0; i < 4; ++i)
#pragma unroll
        for (int j = 0; j < 4; ++j) acc[i][j] = (f32x4){0.f, 0.f, 0.f, 0.f};

    // staging: chunk = q*256 + tid; row = chunk>>2 (of 128); col8 = (chunk&3)*8
    const int r0 = tid >> 2;
    const int c0 = (tid & 3) * 8;
    const bf16* gA0 = A  + (size_t)(m0 + r0) * KDIM + c0;
    const bf16* gA1 = A  + (size_t)(m0 + 64 + r0) * KDIM + c0;
    const bf16* gB0 = Bm + (size_t)(n0 + r0) * KDIM + c0;
    const bf16* gB1 = Bm + (size_t)(n0 + 64 + r0) * KDIM + c0;
    bf16* lAq0 = &lA[(size_t)(wid * 64) * 8];
    bf16* lAq1 = &lA[(size_t)(256 + wid * 64) * 8];
    bf16* lBq0 = &lB[(size_t)(wid * 64) * 8];
    bf16* lBq1 = &lB[(size_t)(256 + wid * 64) * 8];

    for (int kt = 0; kt < KDIM / 32; ++kt) {
        const int ko = kt * 32;
        async_load16(gA0 + ko, lAq0);
        async_load16(gA1 + ko, lAq1);
        async_load16(gB0 + ko, lBq0);
        async_load16(gB1 + ko, lBq1);
        __syncthreads();   // compiler drains vmcnt(0) before s_barrier

        bf16x8 af[4], bfr[4];
#pragma unroll
        for (int mi = 0; mi < 4; ++mi)
            af[mi] = *(const bf16x8*)&lA[(size_t)(wr * 64 + mi * 16 + lrow) * 32 + lkg * 8];
#pragma unroll
        for (int ni = 0; ni < 4; ++ni)
            bfr[ni] = *(const bf16x8*)&lB[(size_t)(wc * 64 + ni * 16 + lrow) * 32 + lkg * 8];

#pragma unroll
        for (int mi = 0; mi < 4; ++mi)
#pragma unroll
            for (int ni = 0; ni < 4; ++ni)
                acc[mi][ni] = __builtin_amdgcn_mfma_f32_16x16x32_bf16(
                    af[mi], bfr[ni], acc[mi][ni], 0, 0, 0);
        __syncthreads();
    }

    // epilogue. acc D-layout: row = rb + r with rb = m0+wr*64+mi*16+lkg*4,
    // col = n0 + wc*64 + ni*16 + lrow   [measured m89/m91]
    if constexpr (EPI == 0) {
        // ---- fused LSTM cell ----
        float* cbuf = (float*)smem;            // [64][132] f32, aliases lA/lB
        float bs[4];
#pragma unroll
        for (int ni = 0; ni < 4; ++ni) bs[ni] = bias[n0 + wc * 64 + ni * 16 + lrow];

        const int lr_rd  = tid >> 2;           // 0..63: LDS row this thread reads
        const int jb8    = (tid & 3) * 8;      // local j base (8 j's per thread)
        const int jg0    = n0 >> 2;            // global j base of this block
        const int tt     = tpar;

#pragma unroll
        for (int p = 0; p < 2; ++p) {
            // stage fragments mi = 2p, 2p+1 (+bias) into cbuf
#pragma unroll
            for (int mm = 0; mm < 2; ++mm) {
#pragma unroll
                for (int ni = 0; ni < 4; ++ni) {
                    const f32x4 v = acc[2 * p + mm][ni];
                    const int lrr = wr * 32 + mm * 16 + lkg * 4;
                    const int lc  = wc * 64 + ni * 16 + lrow;
#pragma unroll
                    for (int r = 0; r < 4; ++r)
                        cbuf[(lrr + r) * 132 + lc] = v[r] + bs[ni];
                }
            }
            __syncthreads();
            // cell: 64 rows x 32 j's; thread -> (row lr_rd, j's jb8..jb8+7)
            const int grow = m0 + 32 * p + lr_rd + (lr_rd & 32);
            const float* rowp = cbuf + lr_rd * 132;
#pragma unroll
            for (int q = 0; q < 8; ++q) {
                const f32x4 v = *(const f32x4*)&rowp[(jb8 + q) * 4];
                const float gi = sigf(v[0]);
                const float gf = sigf(v[1]);
                const float gg = tanh_stable(v[2]);
                const float go = sigf(v[3]);
                const int j = jg0 + jb8 + q;
                const size_t off = (size_t)grow * 1024 + j;
                const float cold = (tt == 0) ? 0.f : cstate[off];
                const float cn = gf * cold + gi * gg;
                const float hn = go * tanh_stable(cn);
                cstate[off] = cn;
                const bf16 hb = __float2bfloat16(hn);
                hout[off] = hb;
                hsb[(size_t)((grow << 3) + (tt & 7)) * 1024 + j] = hb;
            }
            __syncthreads();   // before pass 1 overwrites cbuf
        }
    } else {
#pragma unroll
        for (int mi = 0; mi < 4; ++mi) {
#pragma unroll
            for (int ni = 0; ni < 4; ++ni) {
                const f32x4 v = acc[mi][ni];
                const int c = n0 + wc * 64 + ni * 16 + lrow;
                const int rb = m0 + wr * 64 + mi * 16 + lkg * 4;
                const float bsv = bias[c];
#pragma unroll
                for (int r = 0; r < 4; ++r) {
                    const float val = v[r] + bsv;
                    const int row = rb + r;
                    if constexpr (EPI == 1) {
                        ((bf16*)Cout)[(size_t)row * 1024 + c] =
                            __float2bfloat16(val > 0.f ? val : 0.f);
                    } else {
                        const int orow = (row >> 3) * TSTEPS + tpar + (row & 7);
                        ((float*)Cout)[(size_t)orow * OUTDIM + c] = val;
                    }
                }
            }
        }
    }
}

// ---------------------------------------------------------------------------
// prep: Wc_perm[j*4+g] = bf16(W_ih[g*1024+j] + W_hh[g*1024+j]); bc_perm same.
// ---------------------------------------------------------------------------
__global__ void prep_wc(const float* __restrict__ Wih, const float* __restrict__ Whh,
                        const float* __restrict__ bih, const float* __restrict__ bhh,
                        bf16* __restrict__ Wc, float* __restrict__ bc) {
    const int base = (blockIdx.x * 256 + threadIdx.x) * 4;   // over 4H*H
    const int r = base >> 10;          // original row g*1024+j
    const int k = base & 1023;
    const int pr = (r & 1023) * 4 + (r >> 10);
    const float4 a = *(const float4*)(Wih + base);
    const float4 b = *(const float4*)(Whh + base);
    bf16* d = Wc + (size_t)pr * 1024 + k;
    d[0] = __float2bfloat16(a.x + b.x);
    d[1] = __float2bfloat16(a.y + b.y);
    d[2] = __float2bfloat16(a.z + b.z);
    d[3] = __float2bfloat16(a.w + b.w);
    if (base < 4096) {
#pragma unroll
        for (int s = 0; s < 4; ++s) {
            const int e = base + s;
            bc[(e & 1023) * 4 + (e >> 10)] = bih[e] + bhh[e];
        }
    }
}

__global__ void f2b(const float* __restrict__ s, bf16* __restrict__ d, int n) {
    const int i = (blockIdx.x * 256 + threadIdx.x) * 4;
    if (i < n) {
        const float4 v = *(const float4*)(s + i);
        d[i + 0] = __float2bfloat16(v.x);
        d[i + 1] = __float2bfloat16(v.y);
        d[i + 2] = __float2bfloat16(v.z);
        d[i + 3] = __float2bfloat16(v.w);
    }
}

// ---------------------------------------------------------------------------
extern "C" void kernel_launch(void* const* d_in, const int* in_sizes, int n_in,
                              void* d_out, int out_size, void* d_ws, size_t ws_size,
                              hipStream_t stream) {
    const float* x     = (const float*)d_in[0];
    const float* W_in  = (const float*)d_in[1];
    const float* b_in  = (const float*)d_in[2];
    const float* W_ih  = (const float*)d_in[3];
    const float* b_ih  = (const float*)d_in[4];
    const float* W_hh  = (const float*)d_in[5];
    const float* b_hh  = (const float*)d_in[6];
    const float* W_out = (const float*)d_in[7];
    const float* b_out = (const float*)d_in[8];
    float* out = (float*)d_out;

    // workspace carve (~63 MB)
    char* ws = (char*)d_ws;
    bf16* Wc   = (bf16*)ws;  ws += (size_t)4096 * 1024 * 2;         //  8 MB (permuted)
    bf16* Wi_b = (bf16*)ws;  ws += (size_t)1024 * 1024 * 2;         //  2 MB
    bf16* Wo_b = (bf16*)ws;  ws += (size_t)512  * 1024 * 2;         //  1 MB
    bf16* x_b  = (bf16*)ws;  ws += (size_t)2048 * 1024 * 2;         //  4 MB
    bf16* hb0  = (bf16*)ws;  ws += (size_t)2048 * 1024 * 2;         //  4 MB (h ping)
    bf16* hb1  = (bf16*)ws;  ws += (size_t)2048 * 1024 * 2;         //  4 MB (h pong)
    bf16* hs   = (bf16*)ws;  ws += (size_t)2048 * CHUNK * 1024 * 2; // 32 MB
    float* bc  = (float*)ws; ws += (size_t)4096 * 4;                // 16 KB (permuted)
    float* cst = (float*)ws; ws += (size_t)2048 * 1024 * 4;         //  8 MB

    // 1) prep
    prep_wc<<<4096 * 1024 / (256 * 4), 256, 0, stream>>>(W_ih, W_hh, b_ih, b_hh, Wc, bc);
    f2b<<<2048 * 1024 / (256 * 4), 256, 0, stream>>>(x, x_b, 2048 * 1024);
    f2b<<<1024 * 1024 / (256 * 4), 256, 0, stream>>>(W_in, Wi_b, 1024 * 1024);
    f2b<<<512 * 1024 / (256 * 4), 256, 0, stream>>>(W_out, Wo_b, 512 * 1024);

    // 2) h0 = relu(x @ W_in^T + b_in) -> hb0
    {
        dim3 g(HIDDIM / 128, BATCH / 128);   // (8,16)
        gemm_k1024<1><<<g, 256, 0, stream>>>(x_b, Wi_b, b_in, hb0,
                                             nullptr, nullptr, nullptr, 0);
    }

    // 3) T recurrent steps: fused gates-GEMM + cell. h double-buffered
    //    (epilogue writes h while other blocks still read it otherwise).
    for (int t = 0; t < TSTEPS; ++t) {
        bf16* h_in  = (t & 1) ? hb1 : hb0;
        bf16* h_out = (t & 1) ? hb0 : hb1;
        {
            dim3 g(4096 / 128, BATCH / 128); // (32,16)
            gemm_k1024<0><<<g, 256, 0, stream>>>(h_in, Wc, bc, nullptr,
                                                 cst, h_out, hs, t);
        }
        if ((t & (CHUNK - 1)) == (CHUNK - 1)) {
            dim3 g(OUTDIM / 128, BATCH * CHUNK / 128); // (4,128)
            gemm_k1024<2><<<g, 256, 0, stream>>>(hs, Wo_b, b_out, out,
                                                 nullptr, nullptr, nullptr,
                                                 t - (CHUNK - 1));
        }
    }
    (void)in_sizes; (void)n_in; (void)out_size; (void)ws_size;
}

// Round 3
// 1326.326 us; speedup vs baseline: 1.1479x; 1.1197x over previous
//
#include <hip/hip_runtime.h>
#include <hip/hip_bf16.h>
#include <cstdint>
#include <cstddef>

// Problem dims (fixed).
#define BATCH   2048
#define HIDDIM  1024
#define TSTEPS  32
#define OUTDIM  512
#define KDIM    1024
#define HS_SLOTS 9      // 9-slot ring: fused out-GEMM at step t reads slots of
                        // steps t-8..t-1 while gates write slot t%9 (disjoint).

using bf16 = __hip_bfloat16;
typedef __bf16 bf16x8 __attribute__((ext_vector_type(8)));
typedef float  f32x4  __attribute__((ext_vector_type(4)));

__device__ __forceinline__ void async_load16(const void* g, void* l) {
    __builtin_amdgcn_global_load_lds(
        (__attribute__((address_space(1))) unsigned int*)(g),
        (__attribute__((address_space(3))) unsigned int*)(l),
        16, 0, 0);
}

__device__ __forceinline__ float sigf(float x) {
    return 1.f / (1.f + __expf(-x));
}
__device__ __forceinline__ float tanh_stable(float x) {
    const float a = __builtin_fabsf(x);
    const float e = __expf(2.f * a);
    const float r = 1.f - 2.f / (e + 1.f);
    return __builtin_copysignf(r, x);
}

// ---------------------------------------------------------------------------
// Main step kernel. 512 threads = 8 waves (2M x 4N, 64x64 per wave).
// Tile BM=128 x BN=256, BK=32. 2-phase double-buffered LDS (48 KB):
//   lA[2]: 128x32 bf16 (8 KB each) | lB[2]: 256x32 bf16 (16 KB each)
// Mainloop per K-step: STAGE(next) -> ds_read+16 MFMA/wave -> 1 barrier.
// Blocks [0, gates_blocks): gates GEMM (h_in @ Wc^T) + fused LSTM cell.
//   Wc rows permuted p=j*4+g so each block owns 64 complete hidden units.
// Blocks [gates_blocks, ...): output GEMM chunk (hs @ Wo^T) for t0..t0+7,
//   A rows remapped through the 9-slot hs ring.
// ---------------------------------------------------------------------------
__launch_bounds__(512, 2)
__global__ void lstm_step(const bf16* __restrict__ h_in, const bf16* __restrict__ Wc,
                          const float* __restrict__ bc,
                          float* __restrict__ cstate, bf16* __restrict__ h_out,
                          bf16* __restrict__ hs, int t, int slot,
                          const bf16* __restrict__ Wo, const float* __restrict__ b_out,
                          float* __restrict__ out, int t0, int gates_blocks) {
    __shared__ __align__(16) char smem[49152];
    bf16* lA = (bf16*)smem;                 // [2][128*32]  @ 0, 8192
    bf16* lB = (bf16*)(smem + 16384);       // [2][256*32]  @ 16384, 32768

    const int tid  = threadIdx.x;
    const int wid  = tid >> 6;
    const int lane = tid & 63;
    const int wr   = wid >> 2;              // 0..1
    const int wc   = wid & 3;               // 0..3
    const int lrow = lane & 15;
    const int lkg  = lane >> 4;

    const int bid   = blockIdx.x;
    const bool is_out = (bid >= gates_blocks);

    int m0, n0;
    const bf16* Abase;
    const bf16* Bbase;
    const float* bias;
    if (!is_out) {
        n0 = (bid & 15) * 256;              // over 4096 gate cols
        m0 = (bid >> 4) * 128;              // over 2048 batch rows
        Abase = h_in; Bbase = Wc; bias = bc;
    } else {
        const int ob = bid - gates_blocks;
        n0 = (ob & 1) * 256;                // over 512 out cols
        m0 = (ob >> 1) * 128;               // over 16384 chunk rows (b*8+tau)
        Abase = hs; Bbase = Wo; bias = b_out;
    }

    // per-lane bias (per ni fragment column)
    float bs[4];
#pragma unroll
    for (int ni = 0; ni < 4; ++ni) bs[ni] = bias[n0 + wc * 64 + ni * 16 + lrow];

    // ---- staging addresses ----
    const int r0 = tid >> 2;                // 0..127
    const int c0 = (tid & 3) * 8;
    int arow;
    if (!is_out) {
        arow = m0 + r0;
    } else {
        const int rr = m0 + r0;             // chunk row b*8+tau
        arow = (rr >> 3) * HS_SLOTS + (t0 + (rr & 7)) % HS_SLOTS;
    }
    const bf16* gA  = Abase + (size_t)arow * KDIM + c0;
    const bf16* gB0 = Bbase + (size_t)(n0 + r0) * KDIM + c0;
    const bf16* gB1 = Bbase + (size_t)(n0 + 128 + r0) * KDIM + c0;

    f32x4 acc[4][4];
#pragma unroll
    for (int i = 0; i < 4; ++i)
#pragma unroll
        for (int j = 0; j < 4; ++j) acc[i][j] = (f32x4){0.f, 0.f, 0.f, 0.f};

    // ---- 2-phase mainloop ----
    // STAGE(buf, ko): A 1 load/thread, B 2 loads/thread; wave-uniform LDS base.
    auto STAGE = [&](int buf, int ko) {
        bf16* a_d = lA + buf * 4096 + wid * 512;          // wave segment
        bf16* b_d0 = lB + buf * 8192 + wid * 512;
        bf16* b_d1 = lB + buf * 8192 + 4096 + wid * 512;
        async_load16(gA + ko, a_d);
        async_load16(gB0 + ko, b_d0);
        async_load16(gB1 + ko, b_d1);
    };

    STAGE(0, 0);
    __syncthreads();                         // drains vmcnt(0): buf0 ready
    int cur = 0;
    for (int kt = 0; kt < KDIM / 32; ++kt) {
        if (kt < KDIM / 32 - 1) STAGE(cur ^ 1, (kt + 1) * 32);
        const bf16* bufA = lA + cur * 4096;
        const bf16* bufB = lB + cur * 8192;
        bf16x8 af[4], bfr[4];
#pragma unroll
        for (int mi = 0; mi < 4; ++mi)
            af[mi] = *(const bf16x8*)&bufA[(wr * 64 + mi * 16 + lrow) * 32 + lkg * 8];
#pragma unroll
        for (int ni = 0; ni < 4; ++ni)
            bfr[ni] = *(const bf16x8*)&bufB[(wc * 64 + ni * 16 + lrow) * 32 + lkg * 8];
#pragma unroll
        for (int mi = 0; mi < 4; ++mi)
#pragma unroll
            for (int ni = 0; ni < 4; ++ni)
                acc[mi][ni] = __builtin_amdgcn_mfma_f32_16x16x32_bf16(
                    af[mi], bfr[ni], acc[mi][ni], 0, 0, 0);
        __syncthreads();                     // stage complete + reads done
        cur ^= 1;
    }

    // ---- epilogues ----
    // acc D-layout: row = m0 + wr*64 + mi*16 + lkg*4 + r, col = n0 + wc*64 + ni*16 + lrow
    if (!is_out) {
        // fused LSTM cell: stage 32-row x 256-col f32 patches (pitch 260) x4 passes
        float* cbuf = (float*)smem;
        const int lrd = tid >> 4;            // 0..31 row within pass
        const int j4  = (tid & 15) * 4;      // local j (x4)
        const int jg0 = n0 >> 2;
#pragma unroll
        for (int p = 0; p < 4; ++p) {
            if (wr == (p >> 1)) {
#pragma unroll
                for (int mm = 0; mm < 2; ++mm) {
                    const int mi = ((p & 1) << 1) | mm;
#pragma unroll
                    for (int ni = 0; ni < 4; ++ni) {
                        const int lc = wc * 64 + ni * 16 + lrow;
#pragma unroll
                        for (int r = 0; r < 4; ++r) {
                            const int lpr = mm * 16 + lkg * 4 + r;
                            cbuf[lpr * 260 + lc] = acc[mi][ni][r] + bs[ni];
                        }
                    }
                }
            }
            __syncthreads();
            const int grow = m0 + p * 32 + lrd;
            const float* rowp = cbuf + lrd * 260;
#pragma unroll
            for (int q = 0; q < 4; ++q) {
                const f32x4 v = *(const f32x4*)&rowp[(j4 + q) * 4];
                const float gi = sigf(v[0]);
                const float gf = sigf(v[1]);
                const float gg = tanh_stable(v[2]);
                const float go = sigf(v[3]);
                const int j = jg0 + j4 + q;
                const size_t off = (size_t)grow * 1024 + j;
                const float cold = (t == 0) ? 0.f : cstate[off];
                const float cn = gf * cold + gi * gg;
                const float hn = go * tanh_stable(cn);
                cstate[off] = cn;
                const bf16 hb = __float2bfloat16(hn);
                h_out[off] = hb;
                hs[((size_t)grow * HS_SLOTS + slot) * 1024 + j] = hb;
            }
            __syncthreads();
        }
    } else {
#pragma unroll
        for (int mi = 0; mi < 4; ++mi) {
#pragma unroll
            for (int ni = 0; ni < 4; ++ni) {
                const f32x4 v = acc[mi][ni];
                const int c = n0 + wc * 64 + ni * 16 + lrow;
                const int rb = m0 + wr * 64 + mi * 16 + lkg * 4;
#pragma unroll
                for (int r = 0; r < 4; ++r) {
                    const int row = rb + r;                      // b*8+tau
                    const int orow = (row >> 3) * TSTEPS + t0 + (row & 7);
                    out[(size_t)orow * OUTDIM + c] = v[r] + bs[ni];
                }
            }
        }
    }
}

// ---------------------------------------------------------------------------
// h0 GEMM (proven R2 structure): 256 thr, 128x128, BK=32, relu-bf16 epilogue.
// ---------------------------------------------------------------------------
__launch_bounds__(256, 2)
__global__ void gemm_h0(const bf16* __restrict__ A, const bf16* __restrict__ Bm,
                        const float* __restrict__ bias, bf16* __restrict__ C) {
    __shared__ __align__(16) bf16 lA[128 * 32];
    __shared__ __align__(16) bf16 lB[128 * 32];

    const int tid  = threadIdx.x;
    const int wid  = tid >> 6;
    const int lane = tid & 63;
    const int m0   = blockIdx.y * 128;
    const int n0   = blockIdx.x * 128;
    const int wr   = wid >> 1;
    const int wc   = wid & 1;
    const int lrow = lane & 15;
    const int lkg  = lane >> 4;

    f32x4 acc[4][4];
#pragma unroll
    for (int i = 0; i < 4; ++i)
#pragma unroll
        for (int j = 0; j < 4; ++j) acc[i][j] = (f32x4){0.f, 0.f, 0.f, 0.f};

    const int r0 = tid >> 2;
    const int c0 = (tid & 3) * 8;
    const bf16* gA0 = A  + (size_t)(m0 + r0) * KDIM + c0;
    const bf16* gA1 = A  + (size_t)(m0 + 64 + r0) * KDIM + c0;
    const bf16* gB0 = Bm + (size_t)(n0 + r0) * KDIM + c0;
    const bf16* gB1 = Bm + (size_t)(n0 + 64 + r0) * KDIM + c0;
    bf16* lAq0 = &lA[(size_t)(wid * 64) * 8];
    bf16* lAq1 = &lA[(size_t)(256 + wid * 64) * 8];
    bf16* lBq0 = &lB[(size_t)(wid * 64) * 8];
    bf16* lBq1 = &lB[(size_t)(256 + wid * 64) * 8];

    for (int kt = 0; kt < KDIM / 32; ++kt) {
        const int ko = kt * 32;
        async_load16(gA0 + ko, lAq0);
        async_load16(gA1 + ko, lAq1);
        async_load16(gB0 + ko, lBq0);
        async_load16(gB1 + ko, lBq1);
        __syncthreads();
        bf16x8 af[4], bfr[4];
#pragma unroll
        for (int mi = 0; mi < 4; ++mi)
            af[mi] = *(const bf16x8*)&lA[(size_t)(wr * 64 + mi * 16 + lrow) * 32 + lkg * 8];
#pragma unroll
        for (int ni = 0; ni < 4; ++ni)
            bfr[ni] = *(const bf16x8*)&lB[(size_t)(wc * 64 + ni * 16 + lrow) * 32 + lkg * 8];
#pragma unroll
        for (int mi = 0; mi < 4; ++mi)
#pragma unroll
            for (int ni = 0; ni < 4; ++ni)
                acc[mi][ni] = __builtin_amdgcn_mfma_f32_16x16x32_bf16(
                    af[mi], bfr[ni], acc[mi][ni], 0, 0, 0);
        __syncthreads();
    }
#pragma unroll
    for (int mi = 0; mi < 4; ++mi) {
#pragma unroll
        for (int ni = 0; ni < 4; ++ni) {
            const f32x4 v = acc[mi][ni];
            const int c = n0 + wc * 64 + ni * 16 + lrow;
            const int rb = m0 + wr * 64 + mi * 16 + lkg * 4;
            const float bsv = bias[c];
#pragma unroll
            for (int r = 0; r < 4; ++r) {
                const float val = v[r] + bsv;
                C[(size_t)(rb + r) * 1024 + c] = __float2bfloat16(val > 0.f ? val : 0.f);
            }
        }
    }
}

// ---------------------------------------------------------------------------
// prep: Wc_perm[j*4+g] = bf16(W_ih[g*1024+j,:] + W_hh[g*1024+j,:]); bc same.
// ---------------------------------------------------------------------------
__global__ void prep_wc(const float* __restrict__ Wih, const float* __restrict__ Whh,
                        const float* __restrict__ bih, const float* __restrict__ bhh,
                        bf16* __restrict__ Wc, float* __restrict__ bc) {
    const int base = (blockIdx.x * 256 + threadIdx.x) * 4;
    const int r = base >> 10;
    const int k = base & 1023;
    const int pr = (r & 1023) * 4 + (r >> 10);
    const float4 a = *(const float4*)(Wih + base);
    const float4 b = *(const float4*)(Whh + base);
    bf16* d = Wc + (size_t)pr * 1024 + k;
    d[0] = __float2bfloat16(a.x + b.x);
    d[1] = __float2bfloat16(a.y + b.y);
    d[2] = __float2bfloat16(a.z + b.z);
    d[3] = __float2bfloat16(a.w + b.w);
    if (base < 4096) {
#pragma unroll
        for (int s = 0; s < 4; ++s) {
            const int e = base + s;
            bc[(e & 1023) * 4 + (e >> 10)] = bih[e] + bhh[e];
        }
    }
}

__global__ void f2b(const float* __restrict__ s, bf16* __restrict__ d, int n) {
    const int i = (blockIdx.x * 256 + threadIdx.x) * 4;
    if (i < n) {
        const float4 v = *(const float4*)(s + i);
        d[i + 0] = __float2bfloat16(v.x);
        d[i + 1] = __float2bfloat16(v.y);
        d[i + 2] = __float2bfloat16(v.z);
        d[i + 3] = __float2bfloat16(v.w);
    }
}

// ---------------------------------------------------------------------------
extern "C" void kernel_launch(void* const* d_in, const int* in_sizes, int n_in,
                              void* d_out, int out_size, void* d_ws, size_t ws_size,
                              hipStream_t stream) {
    const float* x     = (const float*)d_in[0];
    const float* W_in  = (const float*)d_in[1];
    const float* b_in  = (const float*)d_in[2];
    const float* W_ih  = (const float*)d_in[3];
    const float* b_ih  = (const float*)d_in[4];
    const float* W_hh  = (const float*)d_in[5];
    const float* b_hh  = (const float*)d_in[6];
    const float* W_out = (const float*)d_in[7];
    const float* b_out = (const float*)d_in[8];
    float* out = (float*)d_out;

    // workspace carve (~67 MB)
    char* ws = (char*)d_ws;
    bf16* Wc   = (bf16*)ws;  ws += (size_t)4096 * 1024 * 2;             //  8 MB (permuted)
    bf16* Wi_b = (bf16*)ws;  ws += (size_t)1024 * 1024 * 2;             //  2 MB
    bf16* Wo_b = (bf16*)ws;  ws += (size_t)512  * 1024 * 2;             //  1 MB
    bf16* x_b  = (bf16*)ws;  ws += (size_t)2048 * 1024 * 2;             //  4 MB
    bf16* hb0  = (bf16*)ws;  ws += (size_t)2048 * 1024 * 2;             //  4 MB
    bf16* hb1  = (bf16*)ws;  ws += (size_t)2048 * 1024 * 2;             //  4 MB
    bf16* hs   = (bf16*)ws;  ws += (size_t)2048 * HS_SLOTS * 1024 * 2;  // 36 MB
    float* bc  = (float*)ws; ws += (size_t)4096 * 4;                    // 16 KB
    float* cst = (float*)ws; ws += (size_t)2048 * 1024 * 4;             //  8 MB

    prep_wc<<<4096 * 1024 / (256 * 4), 256, 0, stream>>>(W_ih, W_hh, b_ih, b_hh, Wc, bc);
    f2b<<<2048 * 1024 / (256 * 4), 256, 0, stream>>>(x, x_b, 2048 * 1024);
    f2b<<<1024 * 1024 / (256 * 4), 256, 0, stream>>>(W_in, Wi_b, 1024 * 1024);
    f2b<<<512 * 1024 / (256 * 4), 256, 0, stream>>>(W_out, Wo_b, 512 * 1024);

    // h0 = relu(x @ W_in^T + b_in) -> hb0
    {
        dim3 g(HIDDIM / 128, BATCH / 128);
        gemm_h0<<<g, 256, 0, stream>>>(x_b, Wi_b, b_in, hb0);
    }

    // recurrent steps; out-GEMM chunks fused as extra blocks at t=8,16,24
    for (int t = 0; t < TSTEPS; ++t) {
        bf16* h_in  = (t & 1) ? hb1 : hb0;
        bf16* h_out = (t & 1) ? hb0 : hb1;
        const bool fuse = (t == 8 || t == 16 || t == 24);
        const int blocks = fuse ? 512 : 256;
        lstm_step<<<blocks, 512, 0, stream>>>(h_in, Wc, bc, cst, h_out, hs,
                                              t, t % HS_SLOTS,
                                              Wo_b, b_out, out, t - 8, 256);
    }
    // tail chunk (steps 24..31)
    lstm_step<<<256, 512, 0, stream>>>(hb0, Wc, bc, cst, hb1, hs,
                                       0, 0, Wo_b, b_out, out, 24, 0);
    (void)in_sizes; (void)n_in; (void)out_size; (void)ws_size;
}

// Round 4
// 1200.246 us; speedup vs baseline: 1.2685x; 1.1050x over previous
//
#include <hip/hip_runtime.h>
#include <hip/hip_bf16.h>
#include <cstdint>
#include <cstddef>

// Problem dims (fixed).
#define BATCH   2048
#define HIDDIM  1024
#define TSTEPS  32
#define OUTDIM  512
#define KDIM    1024
#define HS_SLOTS 9      // 9-slot ring: fused out-GEMM at step t reads slots of
                        // steps t-8..t-1 while gates write slot t%9 (disjoint).

using bf16 = __hip_bfloat16;
typedef __bf16 bf16x8 __attribute__((ext_vector_type(8)));
typedef float  f32x4  __attribute__((ext_vector_type(4)));

__device__ __forceinline__ void async_load16(const void* g, void* l) {
    __builtin_amdgcn_global_load_lds(
        (__attribute__((address_space(1))) unsigned int*)(g),
        (__attribute__((address_space(3))) unsigned int*)(l),
        16, 0, 0);
}

__device__ __forceinline__ float sigf(float x) {
    return 1.f / (1.f + __expf(-x));
}
__device__ __forceinline__ float tanh_stable(float x) {
    const float a = __builtin_fabsf(x);
    const float e = __expf(2.f * a);
    const float r = 1.f - 2.f / (e + 1.f);
    return __builtin_copysignf(r, x);
}

// ---------------------------------------------------------------------------
// Main step kernel. 512 threads = 8 waves (2M x 4N, 64x64 per wave).
// Tile BM=128 x BN=256, BK=32. 3-deep counted-vmcnt pipeline (T3+T4):
//   LDS 72 KB: lA[3] 128x32 bf16 (8 KB each) | lB[3] 256x32 bf16 (16 KB each)
// Per iter: vmcnt(6) [oldest tile done, 6 loads in flight] -> s_barrier ->
//   ds_read + MFMA (setprio) -> s_barrier -> STAGE(kt+3 -> freed buf).
// vmcnt counts ONLY staging loads: 3 global_load_lds per wave per tile;
// bias loads deferred to epilogue so the count stays exact.
// Blocks [0, gates_blocks): gates GEMM (h_in @ Wc^T) + fused LSTM cell.
// Blocks [gates_blocks, ...): output GEMM chunk (hs ring @ Wo^T).
// ---------------------------------------------------------------------------
#define MAINLOOP_ITER(VMNT)                                                    \
    asm volatile("s_waitcnt vmcnt(" VMNT ")" ::: "memory");                    \
    __builtin_amdgcn_s_barrier();                                              \
    __builtin_amdgcn_sched_barrier(0);                                         \
    {                                                                          \
        const bf16* bufA_ = lA + cur * 4096;                                   \
        const bf16* bufB_ = lB + cur * 8192;                                   \
        bf16x8 af[4], bfr[4];                                                  \
        _Pragma("unroll")                                                      \
        for (int mi = 0; mi < 4; ++mi)                                         \
            af[mi] = *(const bf16x8*)&bufA_[(wr * 64 + mi * 16 + lrow) * 32 + lkg * 8];  \
        _Pragma("unroll")                                                      \
        for (int ni = 0; ni < 4; ++ni)                                         \
            bfr[ni] = *(const bf16x8*)&bufB_[(wc * 64 + ni * 16 + lrow) * 32 + lkg * 8]; \
        __builtin_amdgcn_s_setprio(1);                                         \
        _Pragma("unroll")                                                      \
        for (int mi = 0; mi < 4; ++mi) {                                       \
            _Pragma("unroll")                                                  \
            for (int ni = 0; ni < 4; ++ni)                                     \
                acc[mi][ni] = __builtin_amdgcn_mfma_f32_16x16x32_bf16(         \
                    af[mi], bfr[ni], acc[mi][ni], 0, 0, 0);                    \
        }                                                                      \
        __builtin_amdgcn_s_setprio(0);                                         \
    }                                                                          \
    __builtin_amdgcn_sched_barrier(0);                                         \
    __builtin_amdgcn_s_barrier();

__launch_bounds__(512, 2)
__global__ void lstm_step(const bf16* __restrict__ h_in, const bf16* __restrict__ Wc,
                          const float* __restrict__ bc,
                          float* __restrict__ cstate, bf16* __restrict__ h_out,
                          bf16* __restrict__ hs, int t, int slot,
                          const bf16* __restrict__ Wo, const float* __restrict__ b_out,
                          float* __restrict__ out, int t0, int gates_blocks) {
    __shared__ __align__(16) char smem[73728];
    bf16* lA = (bf16*)smem;                 // 3 bufs @ 0, 8K, 16K
    bf16* lB = (bf16*)(smem + 24576);       // 3 bufs @ 24K, 40K, 56K

    const int tid  = threadIdx.x;
    const int wid  = tid >> 6;
    const int lane = tid & 63;
    const int wr   = wid >> 2;              // 0..1
    const int wc   = wid & 3;               // 0..3
    const int lrow = lane & 15;
    const int lkg  = lane >> 4;

    const int bid   = blockIdx.x;
    const bool is_out = (bid >= gates_blocks);

    int m0, n0;
    const bf16* Abase;
    const bf16* Bbase;
    const float* bias;
    if (!is_out) {
        n0 = (bid & 15) * 256;              // over 4096 gate cols
        m0 = (bid >> 4) * 128;              // over 2048 batch rows
        Abase = h_in; Bbase = Wc; bias = bc;
    } else {
        const int ob = bid - gates_blocks;
        n0 = (ob & 1) * 256;                // over 512 out cols
        m0 = (ob >> 1) * 128;               // over 16384 chunk rows (b*8+tau)
        Abase = hs; Bbase = Wo; bias = b_out;
    }

    // ---- staging addresses ----
    const int r0 = tid >> 2;                // 0..127
    const int c0 = (tid & 3) * 8;
    int arow;
    if (!is_out) {
        arow = m0 + r0;
    } else {
        const int rr = m0 + r0;             // chunk row b*8+tau
        arow = (rr >> 3) * HS_SLOTS + (t0 + (rr & 7)) % HS_SLOTS;
    }
    const bf16* gA  = Abase + (size_t)arow * KDIM + c0;
    const bf16* gB0 = Bbase + (size_t)(n0 + r0) * KDIM + c0;
    const bf16* gB1 = Bbase + (size_t)(n0 + 128 + r0) * KDIM + c0;

    f32x4 acc[4][4];
#pragma unroll
    for (int i = 0; i < 4; ++i)
#pragma unroll
        for (int j = 0; j < 4; ++j) acc[i][j] = (f32x4){0.f, 0.f, 0.f, 0.f};

    // STAGE(buf, ko): 3 async loads/thread into wave-uniform LDS segments.
    auto STAGE = [&](int buf, int ko) {
        bf16* a_d  = lA + buf * 4096 + wid * 512;
        bf16* b_d0 = lB + buf * 8192 + wid * 512;
        bf16* b_d1 = lB + buf * 8192 + 4096 + wid * 512;
        async_load16(gA + ko, a_d);
        async_load16(gB0 + ko, b_d0);
        async_load16(gB1 + ko, b_d1);
    };

    // prologue: 3 tiles in flight (9 loads/wave outstanding)
    STAGE(0, 0);
    STAGE(1, 32);
    STAGE(2, 64);
    int cur = 0;
    // main: kt = 0..29 at vmcnt(6); stage tile kt+3 for kt <= 28
    for (int kt = 0; kt < 30; ++kt) {
        MAINLOOP_ITER("6")
        if (kt < 29) STAGE(cur, (kt + 3) * 32);
        cur = (cur == 2) ? 0 : cur + 1;
    }
    // tail drain: kt = 30 (2 tiles left), kt = 31 (last)
    MAINLOOP_ITER("3")
    cur = (cur == 2) ? 0 : cur + 1;
    MAINLOOP_ITER("0")
    __builtin_amdgcn_sched_barrier(0);

    // per-lane bias (loaded here so mainloop vmcnt counting stays exact)
    float bs[4];
#pragma unroll
    for (int ni = 0; ni < 4; ++ni) bs[ni] = bias[n0 + wc * 64 + ni * 16 + lrow];

    // ---- epilogues ----
    // acc D-layout: row = m0 + wr*64 + mi*16 + lkg*4 + r, col = n0 + wc*64 + ni*16 + lrow
    if (!is_out) {
        // fused LSTM cell: stage 32-row x 256-col f32 patches (pitch 260) x4 passes
        float* cbuf = (float*)smem;
        const int lrd = tid >> 4;            // 0..31 row within pass
        const int j4  = (tid & 15) * 4;      // local j (x4)
        const int jg0 = n0 >> 2;
#pragma unroll
        for (int p = 0; p < 4; ++p) {
            if (wr == (p >> 1)) {
#pragma unroll
                for (int mm = 0; mm < 2; ++mm) {
                    const int mi = ((p & 1) << 1) | mm;
#pragma unroll
                    for (int ni = 0; ni < 4; ++ni) {
                        const int lc = wc * 64 + ni * 16 + lrow;
#pragma unroll
                        for (int r = 0; r < 4; ++r) {
                            const int lpr = mm * 16 + lkg * 4 + r;
                            cbuf[lpr * 260 + lc] = acc[mi][ni][r] + bs[ni];
                        }
                    }
                }
            }
            __syncthreads();
            const int grow = m0 + p * 32 + lrd;
            const float* rowp = cbuf + lrd * 260;
#pragma unroll
            for (int q = 0; q < 4; ++q) {
                const f32x4 v = *(const f32x4*)&rowp[(j4 + q) * 4];
                const float gi = sigf(v[0]);
                const float gf = sigf(v[1]);
                const float gg = tanh_stable(v[2]);
                const float go = sigf(v[3]);
                const int j = jg0 + j4 + q;
                const size_t off = (size_t)grow * 1024 + j;
                const float cold = (t == 0) ? 0.f : cstate[off];
                const float cn = gf * cold + gi * gg;
                const float hn = go * tanh_stable(cn);
                cstate[off] = cn;
                const bf16 hb = __float2bfloat16(hn);
                h_out[off] = hb;
                hs[((size_t)grow * HS_SLOTS + slot) * 1024 + j] = hb;
            }
            __syncthreads();
        }
    } else {
#pragma unroll
        for (int mi = 0; mi < 4; ++mi) {
#pragma unroll
            for (int ni = 0; ni < 4; ++ni) {
                const f32x4 v = acc[mi][ni];
                const int c = n0 + wc * 64 + ni * 16 + lrow;
                const int rb = m0 + wr * 64 + mi * 16 + lkg * 4;
#pragma unroll
                for (int r = 0; r < 4; ++r) {
                    const int row = rb + r;                      // b*8+tau
                    const int orow = (row >> 3) * TSTEPS + t0 + (row & 7);
                    out[(size_t)orow * OUTDIM + c] = v[r] + bs[ni];
                }
            }
        }
    }
}

// ---------------------------------------------------------------------------
// h0 GEMM (proven R2 structure): 256 thr, 128x128, BK=32, relu-bf16 epilogue.
// ---------------------------------------------------------------------------
__launch_bounds__(256, 2)
__global__ void gemm_h0(const bf16* __restrict__ A, const bf16* __restrict__ Bm,
                        const float* __restrict__ bias, bf16* __restrict__ C) {
    __shared__ __align__(16) bf16 lA[128 * 32];
    __shared__ __align__(16) bf16 lB[128 * 32];

    const int tid  = threadIdx.x;
    const int wid  = tid >> 6;
    const int lane = tid & 63;
    const int m0   = blockIdx.y * 128;
    const int n0   = blockIdx.x * 128;
    const int wr   = wid >> 1;
    const int wc   = wid & 1;
    const int lrow = lane & 15;
    const int lkg  = lane >> 4;

    f32x4 acc[4][4];
#pragma unroll
    for (int i = 0; i < 4; ++i)
#pragma unroll
        for (int j = 0; j < 4; ++j) acc[i][j] = (f32x4){0.f, 0.f, 0.f, 0.f};

    const int r0 = tid >> 2;
    const int c0 = (tid & 3) * 8;
    const bf16* gA0 = A  + (size_t)(m0 + r0) * KDIM + c0;
    const bf16* gA1 = A  + (size_t)(m0 + 64 + r0) * KDIM + c0;
    const bf16* gB0 = Bm + (size_t)(n0 + r0) * KDIM + c0;
    const bf16* gB1 = Bm + (size_t)(n0 + 64 + r0) * KDIM + c0;
    bf16* lAq0 = &lA[(size_t)(wid * 64) * 8];
    bf16* lAq1 = &lA[(size_t)(256 + wid * 64) * 8];
    bf16* lBq0 = &lB[(size_t)(wid * 64) * 8];
    bf16* lBq1 = &lB[(size_t)(256 + wid * 64) * 8];

    for (int kt = 0; kt < KDIM / 32; ++kt) {
        const int ko = kt * 32;
        async_load16(gA0 + ko, lAq0);
        async_load16(gA1 + ko, lAq1);
        async_load16(gB0 + ko, lBq0);
        async_load16(gB1 + ko, lBq1);
        __syncthreads();
        bf16x8 af[4], bfr[4];
#pragma unroll
        for (int mi = 0; mi < 4; ++mi)
            af[mi] = *(const bf16x8*)&lA[(size_t)(wr * 64 + mi * 16 + lrow) * 32 + lkg * 8];
#pragma unroll
        for (int ni = 0; ni < 4; ++ni)
            bfr[ni] = *(const bf16x8*)&lB[(size_t)(wc * 64 + ni * 16 + lrow) * 32 + lkg * 8];
#pragma unroll
        for (int mi = 0; mi < 4; ++mi)
#pragma unroll
            for (int ni = 0; ni < 4; ++ni)
                acc[mi][ni] = __builtin_amdgcn_mfma_f32_16x16x32_bf16(
                    af[mi], bfr[ni], acc[mi][ni], 0, 0, 0);
        __syncthreads();
    }
#pragma unroll
    for (int mi = 0; mi < 4; ++mi) {
#pragma unroll
        for (int ni = 0; ni < 4; ++ni) {
            const f32x4 v = acc[mi][ni];
            const int c = n0 + wc * 64 + ni * 16 + lrow;
            const int rb = m0 + wr * 64 + mi * 16 + lkg * 4;
            const float bsv = bias[c];
#pragma unroll
            for (int r = 0; r < 4; ++r) {
                const float val = v[r] + bsv;
                C[(size_t)(rb + r) * 1024 + c] = __float2bfloat16(val > 0.f ? val : 0.f);
            }
        }
    }
}

// ---------------------------------------------------------------------------
// prep: Wc_perm[j*4+g] = bf16(W_ih[g*1024+j,:] + W_hh[g*1024+j,:]); bc same.
// ---------------------------------------------------------------------------
__global__ void prep_wc(const float* __restrict__ Wih, const float* __restrict__ Whh,
                        const float* __restrict__ bih, const float* __restrict__ bhh,
                        bf16* __restrict__ Wc, float* __restrict__ bc) {
    const int base = (blockIdx.x * 256 + threadIdx.x) * 4;
    const int r = base >> 10;
    const int k = base & 1023;
    const int pr = (r & 1023) * 4 + (r >> 10);
    const float4 a = *(const float4*)(Wih + base);
    const float4 b = *(const float4*)(Whh + base);
    bf16* d = Wc + (size_t)pr * 1024 + k;
    d[0] = __float2bfloat16(a.x + b.x);
    d[1] = __float2bfloat16(a.y + b.y);
    d[2] = __float2bfloat16(a.z + b.z);
    d[3] = __float2bfloat16(a.w + b.w);
    if (base < 4096) {
#pragma unroll
        for (int s = 0; s < 4; ++s) {
            const int e = base + s;
            bc[(e & 1023) * 4 + (e >> 10)] = bih[e] + bhh[e];
        }
    }
}

__global__ void f2b(const float* __restrict__ s, bf16* __restrict__ d, int n) {
    const int i = (blockIdx.x * 256 + threadIdx.x) * 4;
    if (i < n) {
        const float4 v = *(const float4*)(s + i);
        d[i + 0] = __float2bfloat16(v.x);
        d[i + 1] = __float2bfloat16(v.y);
        d[i + 2] = __float2bfloat16(v.z);
        d[i + 3] = __float2bfloat16(v.w);
    }
}

// ---------------------------------------------------------------------------
extern "C" void kernel_launch(void* const* d_in, const int* in_sizes, int n_in,
                              void* d_out, int out_size, void* d_ws, size_t ws_size,
                              hipStream_t stream) {
    const float* x     = (const float*)d_in[0];
    const float* W_in  = (const float*)d_in[1];
    const float* b_in  = (const float*)d_in[2];
    const float* W_ih  = (const float*)d_in[3];
    const float* b_ih  = (const float*)d_in[4];
    const float* W_hh  = (const float*)d_in[5];
    const float* b_hh  = (const float*)d_in[6];
    const float* W_out = (const float*)d_in[7];
    const float* b_out = (const float*)d_in[8];
    float* out = (float*)d_out;

    // workspace carve (~67 MB)
    char* ws = (char*)d_ws;
    bf16* Wc   = (bf16*)ws;  ws += (size_t)4096 * 1024 * 2;             //  8 MB (permuted)
    bf16* Wi_b = (bf16*)ws;  ws += (size_t)1024 * 1024 * 2;             //  2 MB
    bf16* Wo_b = (bf16*)ws;  ws += (size_t)512  * 1024 * 2;             //  1 MB
    bf16* x_b  = (bf16*)ws;  ws += (size_t)2048 * 1024 * 2;             //  4 MB
    bf16* hb0  = (bf16*)ws;  ws += (size_t)2048 * 1024 * 2;             //  4 MB
    bf16* hb1  = (bf16*)ws;  ws += (size_t)2048 * 1024 * 2;             //  4 MB
    bf16* hs   = (bf16*)ws;  ws += (size_t)2048 * HS_SLOTS * 1024 * 2;  // 36 MB
    float* bc  = (float*)ws; ws += (size_t)4096 * 4;                    // 16 KB
    float* cst = (float*)ws; ws += (size_t)2048 * 1024 * 4;             //  8 MB

    prep_wc<<<4096 * 1024 / (256 * 4), 256, 0, stream>>>(W_ih, W_hh, b_ih, b_hh, Wc, bc);
    f2b<<<2048 * 1024 / (256 * 4), 256, 0, stream>>>(x, x_b, 2048 * 1024);
    f2b<<<1024 * 1024 / (256 * 4), 256, 0, stream>>>(W_in, Wi_b, 1024 * 1024);
    f2b<<<512 * 1024 / (256 * 4), 256, 0, stream>>>(W_out, Wo_b, 512 * 1024);

    // h0 = relu(x @ W_in^T + b_in) -> hb0
    {
        dim3 g(HIDDIM / 128, BATCH / 128);
        gemm_h0<<<g, 256, 0, stream>>>(x_b, Wi_b, b_in, hb0);
    }

    // recurrent steps; out-GEMM chunks fused as extra blocks at t=8,16,24
    for (int t = 0; t < TSTEPS; ++t) {
        bf16* h_in  = (t & 1) ? hb1 : hb0;
        bf16* h_out = (t & 1) ? hb0 : hb1;
        const bool fuse = (t == 8 || t == 16 || t == 24);
        const int blocks = fuse ? 512 : 256;
        lstm_step<<<blocks, 512, 0, stream>>>(h_in, Wc, bc, cst, h_out, hs,
                                              t, t % HS_SLOTS,
                                              Wo_b, b_out, out, t - 8, 256);
    }
    // tail chunk (steps 24..31)
    lstm_step<<<256, 512, 0, stream>>>(hb0, Wc, bc, cst, hb1, hs,
                                       0, 0, Wo_b, b_out, out, 24, 0);
    (void)in_sizes; (void)n_in; (void)out_size; (void)ws_size;
}

// Round 5
// 1153.857 us; speedup vs baseline: 1.3195x; 1.0402x over previous
//
#include <hip/hip_runtime.h>
#include <hip/hip_bf16.h>
#include <cstdint>
#include <cstddef>

// Problem dims (fixed).
#define BATCH   2048
#define HIDDIM  1024
#define TSTEPS  32
#define OUTDIM  512
#define KDIM    1024
#define HS_SLOTS 9      // 9-slot ring: fused out-GEMM at step t reads slots of
                        // steps t-8..t-1 while gates write slot t%9 (disjoint).

using bf16 = __hip_bfloat16;
typedef __bf16 bf16x8 __attribute__((ext_vector_type(8)));
typedef float  f32x4  __attribute__((ext_vector_type(4)));

__device__ __forceinline__ void async_load16(const void* g, void* l) {
    __builtin_amdgcn_global_load_lds(
        (__attribute__((address_space(1))) unsigned int*)(g),
        (__attribute__((address_space(3))) unsigned int*)(l),
        16, 0, 0);
}

__device__ __forceinline__ float sigf(float x) {
    return 1.f / (1.f + __expf(-x));
}
__device__ __forceinline__ float tanh_stable(float x) {
    const float a = __builtin_fabsf(x);
    const float e = __expf(2.f * a);
    const float r = 1.f - 2.f / (e + 1.f);
    return __builtin_copysignf(r, x);
}

// ---------------------------------------------------------------------------
// Main step kernel. 512 threads = 8 waves (2M x 4N, 64x64 per wave).
// Tile BM=128 x BN=256, BK=32. 3-deep counted-vmcnt pipeline (T3+T4) +
// T2 bank swizzle. LDS 72 KB: lA[3] 8 KB | lB[3] 16 KB.
//
// Swizzle map (involution, rule #21 both-sides): tile row pitch 64 B = four
// 16 B slots; physical slot' = slot ^ ((row>>1)&3). Unswizzled reads put 8
// lanes on the same 4 banks (8-way, ~2.9x); swizzled = exactly 2 lanes/bank
// (free, m136). Write side: LDS dest stays LINEAR (global_load_lds reqmt);
// the per-lane GLOBAL source column is pre-swizzled instead (m173):
//   c0 = 8 * ((tid&3) ^ ((tid>>3)&3))
// Read side: lkgs = lkg ^ ((lrow>>1)&3) replaces lkg.
// ---------------------------------------------------------------------------
#define MAINLOOP_ITER(VMNT)                                                    \
    asm volatile("s_waitcnt vmcnt(" VMNT ")" ::: "memory");                    \
    __builtin_amdgcn_s_barrier();                                              \
    __builtin_amdgcn_sched_barrier(0);                                         \
    {                                                                          \
        const bf16* bufA_ = lA + cur * 4096;                                   \
        const bf16* bufB_ = lB + cur * 8192;                                   \
        bf16x8 af[4], bfr[4];                                                  \
        _Pragma("unroll")                                                      \
        for (int mi = 0; mi < 4; ++mi)                                         \
            af[mi] = *(const bf16x8*)&bufA_[(wr * 64 + mi * 16 + lrow) * 32 + lkgs * 8];  \
        _Pragma("unroll")                                                      \
        for (int ni = 0; ni < 4; ++ni)                                         \
            bfr[ni] = *(const bf16x8*)&bufB_[(wc * 64 + ni * 16 + lrow) * 32 + lkgs * 8]; \
        __builtin_amdgcn_s_setprio(1);                                         \
        _Pragma("unroll")                                                      \
        for (int mi = 0; mi < 4; ++mi) {                                       \
            _Pragma("unroll")                                                  \
            for (int ni = 0; ni < 4; ++ni)                                     \
                acc[mi][ni] = __builtin_amdgcn_mfma_f32_16x16x32_bf16(         \
                    af[mi], bfr[ni], acc[mi][ni], 0, 0, 0);                    \
        }                                                                      \
        __builtin_amdgcn_s_setprio(0);                                         \
    }                                                                          \
    __builtin_amdgcn_sched_barrier(0);                                         \
    __builtin_amdgcn_s_barrier();

__launch_bounds__(512, 2)
__global__ void lstm_step(const bf16* __restrict__ h_in, const bf16* __restrict__ Wc,
                          const float* __restrict__ bc,
                          float* __restrict__ cstate, bf16* __restrict__ h_out,
                          bf16* __restrict__ hs, int t, int slot,
                          const bf16* __restrict__ Wo, const float* __restrict__ b_out,
                          float* __restrict__ out, int t0, int gates_blocks) {
    __shared__ __align__(16) char smem[73728];
    bf16* lA = (bf16*)smem;                 // 3 bufs @ 0, 8K, 16K
    bf16* lB = (bf16*)(smem + 24576);       // 3 bufs @ 24K, 40K, 56K

    const int tid  = threadIdx.x;
    const int wid  = tid >> 6;
    const int lane = tid & 63;
    const int wr   = wid >> 2;              // 0..1
    const int wc   = wid & 3;               // 0..3
    const int lrow = lane & 15;
    const int lkg  = lane >> 4;
    const int lkgs = lkg ^ ((lrow >> 1) & 3);   // T2 swizzled read slot

    const int bid   = blockIdx.x;
    const bool is_out = (bid >= gates_blocks);

    int m0, n0;
    const bf16* Abase;
    const bf16* Bbase;
    const float* bias;
    if (!is_out) {
        n0 = (bid & 15) * 256;              // over 4096 gate cols
        m0 = (bid >> 4) * 128;              // over 2048 batch rows
        Abase = h_in; Bbase = Wc; bias = bc;
    } else {
        const int ob = bid - gates_blocks;
        n0 = (ob & 1) * 256;                // over 512 out cols
        m0 = (ob >> 1) * 128;               // over 16384 chunk rows (b*8+tau)
        Abase = hs; Bbase = Wo; bias = b_out;
    }

    // ---- staging addresses (source col pre-swizzled; LDS dest linear) ----
    const int r0 = tid >> 2;                // 0..127 physical tile row
    const int c0 = ((tid & 3) ^ ((tid >> 3) & 3)) * 8;   // swizzled source slot
    int arow;
    if (!is_out) {
        arow = m0 + r0;
    } else {
        const int rr = m0 + r0;             // chunk row b*8+tau
        arow = (rr >> 3) * HS_SLOTS + (t0 + (rr & 7)) % HS_SLOTS;
    }
    const bf16* gA  = Abase + (size_t)arow * KDIM + c0;
    const bf16* gB0 = Bbase + (size_t)(n0 + r0) * KDIM + c0;
    const bf16* gB1 = Bbase + (size_t)(n0 + 128 + r0) * KDIM + c0;

    f32x4 acc[4][4];
#pragma unroll
    for (int i = 0; i < 4; ++i)
#pragma unroll
        for (int j = 0; j < 4; ++j) acc[i][j] = (f32x4){0.f, 0.f, 0.f, 0.f};

    // STAGE(buf, ko): 3 async loads/thread into wave-uniform LDS segments.
    auto STAGE = [&](int buf, int ko) {
        bf16* a_d  = lA + buf * 4096 + wid * 512;
        bf16* b_d0 = lB + buf * 8192 + wid * 512;
        bf16* b_d1 = lB + buf * 8192 + 4096 + wid * 512;
        async_load16(gA + ko, a_d);
        async_load16(gB0 + ko, b_d0);
        async_load16(gB1 + ko, b_d1);
    };

    // prologue: 3 tiles in flight (9 loads/wave outstanding)
    STAGE(0, 0);
    STAGE(1, 32);
    STAGE(2, 64);
    int cur = 0;
    // main: kt = 0..29 at vmcnt(6); stage tile kt+3 for kt <= 28
    for (int kt = 0; kt < 30; ++kt) {
        MAINLOOP_ITER("6")
        if (kt < 29) STAGE(cur, (kt + 3) * 32);
        cur = (cur == 2) ? 0 : cur + 1;
    }
    // tail drain: kt = 30 (2 tiles left), kt = 31 (last)
    MAINLOOP_ITER("3")
    cur = (cur == 2) ? 0 : cur + 1;
    MAINLOOP_ITER("0")
    __builtin_amdgcn_sched_barrier(0);

    // per-lane bias (loaded here so mainloop vmcnt counting stays exact)
    float bs[4];
#pragma unroll
    for (int ni = 0; ni < 4; ++ni) bs[ni] = bias[n0 + wc * 64 + ni * 16 + lrow];

    // ---- epilogues ----
    // acc D-layout: row = m0 + wr*64 + mi*16 + lkg*4 + r, col = n0 + wc*64 + ni*16 + lrow
    if (!is_out) {
        // fused LSTM cell: stage 32-row x 256-col f32 patches (pitch 260) x4 passes
        float* cbuf = (float*)smem;
        const int lrd = tid >> 4;            // 0..31 row within pass
        const int j4  = (tid & 15) * 4;      // local j (x4)
        const int jg0 = n0 >> 2;
#pragma unroll
        for (int p = 0; p < 4; ++p) {
            if (wr == (p >> 1)) {
#pragma unroll
                for (int mm = 0; mm < 2; ++mm) {
                    const int mi = ((p & 1) << 1) | mm;
#pragma unroll
                    for (int ni = 0; ni < 4; ++ni) {
                        const int lc = wc * 64 + ni * 16 + lrow;
#pragma unroll
                        for (int r = 0; r < 4; ++r) {
                            const int lpr = mm * 16 + lkg * 4 + r;
                            cbuf[lpr * 260 + lc] = acc[mi][ni][r] + bs[ni];
                        }
                    }
                }
            }
            __syncthreads();
            const int grow = m0 + p * 32 + lrd;
            const float* rowp = cbuf + lrd * 260;
#pragma unroll
            for (int q = 0; q < 4; ++q) {
                const f32x4 v = *(const f32x4*)&rowp[(j4 + q) * 4];
                const float gi = sigf(v[0]);
                const float gf = sigf(v[1]);
                const float gg = tanh_stable(v[2]);
                const float go = sigf(v[3]);
                const int j = jg0 + j4 + q;
                const size_t off = (size_t)grow * 1024 + j;
                const float cold = (t == 0) ? 0.f : cstate[off];
                const float cn = gf * cold + gi * gg;
                const float hn = go * tanh_stable(cn);
                cstate[off] = cn;
                const bf16 hb = __float2bfloat16(hn);
                h_out[off] = hb;
                hs[((size_t)grow * HS_SLOTS + slot) * 1024 + j] = hb;
            }
            __syncthreads();
        }
    } else {
#pragma unroll
        for (int mi = 0; mi < 4; ++mi) {
#pragma unroll
            for (int ni = 0; ni < 4; ++ni) {
                const f32x4 v = acc[mi][ni];
                const int c = n0 + wc * 64 + ni * 16 + lrow;
                const int rb = m0 + wr * 64 + mi * 16 + lkg * 4;
#pragma unroll
                for (int r = 0; r < 4; ++r) {
                    const int row = rb + r;                      // b*8+tau
                    const int orow = (row >> 3) * TSTEPS + t0 + (row & 7);
                    out[(size_t)orow * OUTDIM + c] = v[r] + bs[ni];
                }
            }
        }
    }
}

// ---------------------------------------------------------------------------
// h0 GEMM (proven R2 structure): 256 thr, 128x128, BK=32, relu-bf16 epilogue.
// ---------------------------------------------------------------------------
__launch_bounds__(256, 2)
__global__ void gemm_h0(const bf16* __restrict__ A, const bf16* __restrict__ Bm,
                        const float* __restrict__ bias, bf16* __restrict__ C) {
    __shared__ __align__(16) bf16 lA[128 * 32];
    __shared__ __align__(16) bf16 lB[128 * 32];

    const int tid  = threadIdx.x;
    const int wid  = tid >> 6;
    const int lane = tid & 63;
    const int m0   = blockIdx.y * 128;
    const int n0   = blockIdx.x * 128;
    const int wr   = wid >> 1;
    const int wc   = wid & 1;
    const int lrow = lane & 15;
    const int lkg  = lane >> 4;

    f32x4 acc[4][4];
#pragma unroll
    for (int i = 0; i < 4; ++i)
#pragma unroll
        for (int j = 0; j < 4; ++j) acc[i][j] = (f32x4){0.f, 0.f, 0.f, 0.f};

    const int r0 = tid >> 2;
    const int c0 = (tid & 3) * 8;
    const bf16* gA0 = A  + (size_t)(m0 + r0) * KDIM + c0;
    const bf16* gA1 = A  + (size_t)(m0 + 64 + r0) * KDIM + c0;
    const bf16* gB0 = Bm + (size_t)(n0 + r0) * KDIM + c0;
    const bf16* gB1 = Bm + (size_t)(n0 + 64 + r0) * KDIM + c0;
    bf16* lAq0 = &lA[(size_t)(wid * 64) * 8];
    bf16* lAq1 = &lA[(size_t)(256 + wid * 64) * 8];
    bf16* lBq0 = &lB[(size_t)(wid * 64) * 8];
    bf16* lBq1 = &lB[(size_t)(256 + wid * 64) * 8];

    for (int kt = 0; kt < KDIM / 32; ++kt) {
        const int ko = kt * 32;
        async_load16(gA0 + ko, lAq0);
        async_load16(gA1 + ko, lAq1);
        async_load16(gB0 + ko, lBq0);
        async_load16(gB1 + ko, lBq1);
        __syncthreads();
        bf16x8 af[4], bfr[4];
#pragma unroll
        for (int mi = 0; mi < 4; ++mi)
            af[mi] = *(const bf16x8*)&lA[(size_t)(wr * 64 + mi * 16 + lrow) * 32 + lkg * 8];
#pragma unroll
        for (int ni = 0; ni < 4; ++ni)
            bfr[ni] = *(const bf16x8*)&lB[(size_t)(wc * 64 + ni * 16 + lrow) * 32 + lkg * 8];
#pragma unroll
        for (int mi = 0; mi < 4; ++mi)
#pragma unroll
            for (int ni = 0; ni < 4; ++ni)
                acc[mi][ni] = __builtin_amdgcn_mfma_f32_16x16x32_bf16(
                    af[mi], bfr[ni], acc[mi][ni], 0, 0, 0);
        __syncthreads();
    }
#pragma unroll
    for (int mi = 0; mi < 4; ++mi) {
#pragma unroll
        for (int ni = 0; ni < 4; ++ni) {
            const f32x4 v = acc[mi][ni];
            const int c = n0 + wc * 64 + ni * 16 + lrow;
            const int rb = m0 + wr * 64 + mi * 16 + lkg * 4;
            const float bsv = bias[c];
#pragma unroll
            for (int r = 0; r < 4; ++r) {
                const float val = v[r] + bsv;
                C[(size_t)(rb + r) * 1024 + c] = __float2bfloat16(val > 0.f ? val : 0.f);
            }
        }
    }
}

// ---------------------------------------------------------------------------
// prep: Wc_perm[j*4+g] = bf16(W_ih[g*1024+j,:] + W_hh[g*1024+j,:]); bc same.
// ---------------------------------------------------------------------------
__global__ void prep_wc(const float* __restrict__ Wih, const float* __restrict__ Whh,
                        const float* __restrict__ bih, const float* __restrict__ bhh,
                        bf16* __restrict__ Wc, float* __restrict__ bc) {
    const int base = (blockIdx.x * 256 + threadIdx.x) * 4;
    const int r = base >> 10;
    const int k = base & 1023;
    const int pr = (r & 1023) * 4 + (r >> 10);
    const float4 a = *(const float4*)(Wih + base);
    const float4 b = *(const float4*)(Whh + base);
    bf16* d = Wc + (size_t)pr * 1024 + k;
    d[0] = __float2bfloat16(a.x + b.x);
    d[1] = __float2bfloat16(a.y + b.y);
    d[2] = __float2bfloat16(a.z + b.z);
    d[3] = __float2bfloat16(a.w + b.w);
    if (base < 4096) {
#pragma unroll
        for (int s = 0; s < 4; ++s) {
            const int e = base + s;
            bc[(e & 1023) * 4 + (e >> 10)] = bih[e] + bhh[e];
        }
    }
}

__global__ void f2b(const float* __restrict__ s, bf16* __restrict__ d, int n) {
    const int i = (blockIdx.x * 256 + threadIdx.x) * 4;
    if (i < n) {
        const float4 v = *(const float4*)(s + i);
        d[i + 0] = __float2bfloat16(v.x);
        d[i + 1] = __float2bfloat16(v.y);
        d[i + 2] = __float2bfloat16(v.z);
        d[i + 3] = __float2bfloat16(v.w);
    }
}

// ---------------------------------------------------------------------------
extern "C" void kernel_launch(void* const* d_in, const int* in_sizes, int n_in,
                              void* d_out, int out_size, void* d_ws, size_t ws_size,
                              hipStream_t stream) {
    const float* x     = (const float*)d_in[0];
    const float* W_in  = (const float*)d_in[1];
    const float* b_in  = (const float*)d_in[2];
    const float* W_ih  = (const float*)d_in[3];
    const float* b_ih  = (const float*)d_in[4];
    const float* W_hh  = (const float*)d_in[5];
    const float* b_hh  = (const float*)d_in[6];
    const float* W_out = (const float*)d_in[7];
    const float* b_out = (const float*)d_in[8];
    float* out = (float*)d_out;

    // workspace carve (~67 MB)
    char* ws = (char*)d_ws;
    bf16* Wc   = (bf16*)ws;  ws += (size_t)4096 * 1024 * 2;             //  8 MB (permuted)
    bf16* Wi_b = (bf16*)ws;  ws += (size_t)1024 * 1024 * 2;             //  2 MB
    bf16* Wo_b = (bf16*)ws;  ws += (size_t)512  * 1024 * 2;             //  1 MB
    bf16* x_b  = (bf16*)ws;  ws += (size_t)2048 * 1024 * 2;             //  4 MB
    bf16* hb0  = (bf16*)ws;  ws += (size_t)2048 * 1024 * 2;             //  4 MB
    bf16* hb1  = (bf16*)ws;  ws += (size_t)2048 * 1024 * 2;             //  4 MB
    bf16* hs   = (bf16*)ws;  ws += (size_t)2048 * HS_SLOTS * 1024 * 2;  // 36 MB
    float* bc  = (float*)ws; ws += (size_t)4096 * 4;                    // 16 KB
    float* cst = (float*)ws; ws += (size_t)2048 * 1024 * 4;             //  8 MB

    prep_wc<<<4096 * 1024 / (256 * 4), 256, 0, stream>>>(W_ih, W_hh, b_ih, b_hh, Wc, bc);
    f2b<<<2048 * 1024 / (256 * 4), 256, 0, stream>>>(x, x_b, 2048 * 1024);
    f2b<<<1024 * 1024 / (256 * 4), 256, 0, stream>>>(W_in, Wi_b, 1024 * 1024);
    f2b<<<512 * 1024 / (256 * 4), 256, 0, stream>>>(W_out, Wo_b, 512 * 1024);

    // h0 = relu(x @ W_in^T + b_in) -> hb0
    {
        dim3 g(HIDDIM / 128, BATCH / 128);
        gemm_h0<<<g, 256, 0, stream>>>(x_b, Wi_b, b_in, hb0);
    }

    // recurrent steps; out-GEMM chunks fused as extra blocks at t=8,16,24
    for (int t = 0; t < TSTEPS; ++t) {
        bf16* h_in  = (t & 1) ? hb1 : hb0;
        bf16* h_out = (t & 1) ? hb0 : hb1;
        const bool fuse = (t == 8 || t == 16 || t == 24);
        const int blocks = fuse ? 512 : 256;
        lstm_step<<<blocks, 512, 0, stream>>>(h_in, Wc, bc, cst, h_out, hs,
                                              t, t % HS_SLOTS,
                                              Wo_b, b_out, out, t - 8, 256);
    }
    // tail chunk (steps 24..31)
    lstm_step<<<256, 512, 0, stream>>>(hb0, Wc, bc, cst, hb1, hs,
                                       0, 0, Wo_b, b_out, out, 24, 0);
    (void)in_sizes; (void)n_in; (void)out_size; (void)ws_size;
}